// Round 3
// baseline (685.379 us; speedup 1.0000x reference)
//
#include <hip/hip_runtime.h>
#include <math.h>

#define HH 7
#define WW 7
#define CC 512
#define HF 64
#define WF 256
#define NS 49            // HH*WW
#define MAXC 196         // max distinct cells = 14 x 14
#define CSTR 40          // cell LDS stride in floats (16B-aligned, bank-spread)
#define CH 32            // channels per staging pass
#define NP4 ((CH * NS) / 4)   // 392 float4 outputs per pass
#define NBINS 2048       // 32 y-bands x 64 x-bins (serpentine)

typedef float floatv4 __attribute__((ext_vector_type(4)));  // native vec for NT store

// Transpose feats (C, HF*WF) -> ws (HF*WF, C) so channel gathers coalesce.
__global__ __launch_bounds__(256) void transpose_feats(const float* __restrict__ in,
                                                       float* __restrict__ out) {
    __shared__ float tile[32][33];
    const int P = HF * WF;  // 16384
    int p  = blockIdx.x * 32 + threadIdx.x;  // spatial index
    int cb = blockIdx.y * 32;                // channel base
#pragma unroll
    for (int r = 0; r < 32; r += 8)
        tile[threadIdx.y + r][threadIdx.x] = in[(size_t)(cb + threadIdx.y + r) * P + p];
    __syncthreads();
    int c  = cb + threadIdx.x;
    int pb = blockIdx.x * 32;
#pragma unroll
    for (int r = 0; r < 32; r += 8)
        out[(size_t)(pb + threadIdx.y + r) * CC + c] = tile[threadIdx.x][threadIdx.y + r];
}

// Spatial bin key: serpentine over (y-band, x-bin).
__device__ __forceinline__ int box_key(const float* __restrict__ boxes, int b,
                                       float sy, float sx) {
    float xc = boxes[b * 4 + 0];
    float yc = boxes[b * 4 + 1];
    int yb = (int)(yc * sy);
    int xb = (int)(xc * sx);
    yb = min(max(yb, 0), 31);
    xb = min(max(xb, 0), 63);
    if (yb & 1) xb = 63 - xb;          // serpentine
    return (yb << 6) | xb;
}

// Single-block counting sort of boxes by spatial bin -> perm (rank -> box id).
__global__ __launch_bounds__(256) void sort_boxes(const float* __restrict__ boxes,
                                                  const int* __restrict__ ih_p,
                                                  const int* __restrict__ iw_p,
                                                  int B, int* __restrict__ perm) {
    __shared__ int hist[NBINS];
    __shared__ int part[256];
    const int tid = threadIdx.x;
    const float sy = 32.0f / (float)ih_p[0];
    const float sx = 64.0f / (float)iw_p[0];

    for (int i = tid; i < NBINS; i += 256) hist[i] = 0;
    __syncthreads();
    for (int b = tid; b < B; b += 256)
        atomicAdd(&hist[box_key(boxes, b, sy, sx)], 1);
    __syncthreads();
    // exclusive prefix sum: 8 bins/thread serial + parallel Hillis-Steele over partials
    const int base = tid * (NBINS / 256);
    int s = 0;
#pragma unroll
    for (int i = 0; i < NBINS / 256; ++i) { int v = hist[base + i]; hist[base + i] = s; s += v; }
    part[tid] = s;
    __syncthreads();
    for (int d = 1; d < 256; d <<= 1) {
        int v = (tid >= d) ? part[tid - d] : 0;
        __syncthreads();
        part[tid] += v;
        __syncthreads();
    }
    const int off = part[tid] - s;   // exclusive prefix of this thread's total
#pragma unroll
    for (int i = 0; i < NBINS / 256; ++i) hist[base + i] += off;
    __syncthreads();
    for (int b = tid; b < B; b += 256) {
        int pos = atomicAdd(&hist[box_key(boxes, b, sy, sx)], 1);
        perm[pos] = b;
    }
}

// box_setup kept for the fallback path.
__device__ __forceinline__ void box_setup(int s, int b,
                                          const float* __restrict__ boxes,
                                          const int* __restrict__ ih_p,
                                          const int* __restrict__ iw_p,
                                          int4* o_out, float4* w_out) {
    int i = s / WW;
    int j = s - i * WW;
    float IW1 = (float)(iw_p[0] - 1);
    float IH1 = (float)(ih_p[0] - 1);
    float xc = boxes[b * 4 + 0];
    float yc = boxes[b * 4 + 1];
    float bw = boxes[b * 4 + 2];
    float bh = boxes[b * 4 + 3];
    float inv_w = 1.0f / IW1;
    float inv_h = 1.0f / IH1;
    float tx = (float)(j - 3) * (1.0f / 3.0f);
    float ty = (float)(i - 3) * (1.0f / 3.0f);
    float gx = (2.0f * xc - IW1) * inv_w + (bw * inv_w) * tx;
    float gy = (2.0f * yc - IH1) * inv_h + (bh * inv_h) * ty;
    float px = (gx + 1.0f) * 0.5f * (float)(WF - 1);
    float py = (gy + 1.0f) * 0.5f * (float)(HF - 1);

    float x0f = floorf(px), y0f = floorf(py);
    float wx1 = px - x0f, wx0 = 1.0f - wx1;
    float wy1 = py - y0f, wy0 = 1.0f - wy1;
    float x1f = x0f + 1.0f, y1f = y0f + 1.0f;

    bool vx0 = (x0f >= 0.0f) && (x0f <= (float)(WF - 1));
    bool vx1 = (x1f >= 0.0f) && (x1f <= (float)(WF - 1));
    bool vy0 = (y0f >= 0.0f) && (y0f <= (float)(HF - 1));
    bool vy1 = (y1f >= 0.0f) && (y1f <= (float)(HF - 1));

    int xi0 = (int)fminf(fmaxf(x0f, 0.0f), (float)(WF - 1));
    int xi1 = (int)fminf(fmaxf(x1f, 0.0f), (float)(WF - 1));
    int yi0 = (int)fminf(fmaxf(y0f, 0.0f), (float)(HF - 1));
    int yi1 = (int)fminf(fmaxf(y1f, 0.0f), (float)(HF - 1));

    int4 o;
    o.x = yi0 * WF + xi0;
    o.y = yi0 * WF + xi1;
    o.z = yi1 * WF + xi0;
    o.w = yi1 * WF + xi1;
    float4 w4;
    w4.x = wx0 * wy0 * ((vx0 && vy0) ? 1.0f : 0.0f);
    w4.y = wx1 * wy0 * ((vx1 && vy0) ? 1.0f : 0.0f);
    w4.z = wx0 * wy1 * ((vx0 && vy1) ? 1.0f : 0.0f);
    w4.w = wx1 * wy1 * ((vx1 && vy1) ? 1.0f : 0.0f);
    *o_out = o;
    *w_out = w4;
}

// One block per box (via perm + bijective XCD chunking). src is transposed
// feats: (HF*WF, CC), channel-contiguous.
// Dedup structure: needed cells = {distinct y corners} x {distinct x corners}
// (exact cross product, since px depends only on j and py only on i).
// Stage nx*ny <= 196 distinct cells per 32-channel pass; compute 49x32 outputs
// from LDS fused into the coalesced NT-store loop.
__global__ __launch_bounds__(256) void roi_pool_v5(const float* __restrict__ src,
                                                   const float* __restrict__ boxes,
                                                   const int* __restrict__ ih_p,
                                                   const int* __restrict__ iw_p,
                                                   const int* __restrict__ perm,
                                                   float* __restrict__ out) {
    __shared__ int    xs_l[14], ys_l[14];       // sorted-distinct corner coords
    __shared__ int    rx_l[7][2], ry_l[7][2];   // per-j / per-i: value -> index
    __shared__ float  wxf[7][2], wyf[7][2];     // validity-folded 1D weights
    __shared__ int    s_nx, s_ny;
    __shared__ int    cell_off4[MAXC];          // float4 offset of cell row in src
    __shared__ int4   s_kq[NS];                 // per-sample cell-index quad
    __shared__ float4 s_wt[NS];                 // per-sample weight quad
    __shared__ float  cell_lds[MAXC * CSTR];    // staged cells, 31.4 KB

    const int nwg  = gridDim.x;
    const int bid  = blockIdx.x;
    const int q    = nwg >> 3, r = nwg & 7;
    const int xcd  = bid & 7, slot = bid >> 3;
    const int rank = xcd * q + min(xcd, r) + slot;
    const int b    = perm[rank];
    const int tid  = threadIdx.x;

    // ---- Phase A: corner candidates + folded 1D weights (j = i = tid < 7) ----
    if (tid < 7) {
        float IW1 = (float)(iw_p[0] - 1);
        float IH1 = (float)(ih_p[0] - 1);
        float xc = boxes[b * 4 + 0], yc = boxes[b * 4 + 1];
        float bw = boxes[b * 4 + 2], bh = boxes[b * 4 + 3];
        float t  = (float)(tid - 3) * (1.0f / 3.0f);

        float gx  = (2.0f * xc - IW1) / IW1 + (bw / IW1) * t;
        float px  = (gx + 1.0f) * 0.5f * (float)(WF - 1);
        float x0f = floorf(px);
        float wx1 = px - x0f, wx0 = 1.0f - wx1;
        bool vx0 = (x0f >= 0.0f) && (x0f <= (float)(WF - 1));
        bool vx1 = (x0f + 1.0f >= 0.0f) && (x0f + 1.0f <= (float)(WF - 1));
        int xi0 = (int)fminf(fmaxf(x0f, 0.0f), (float)(WF - 1));
        int xi1 = (int)fminf(fmaxf(x0f + 1.0f, 0.0f), (float)(WF - 1));
        xs_l[2 * tid] = xi0; xs_l[2 * tid + 1] = xi1;
        rx_l[tid][0] = xi0;  rx_l[tid][1] = xi1;        // values (for now)
        wxf[tid][0] = wx0 * (vx0 ? 1.0f : 0.0f);
        wxf[tid][1] = wx1 * (vx1 ? 1.0f : 0.0f);

        float gy  = (2.0f * yc - IH1) / IH1 + (bh / IH1) * t;
        float py  = (gy + 1.0f) * 0.5f * (float)(HF - 1);
        float y0f = floorf(py);
        float wy1v = py - y0f, wy0v = 1.0f - wy1v;
        bool vy0 = (y0f >= 0.0f) && (y0f <= (float)(HF - 1));
        bool vy1 = (y0f + 1.0f >= 0.0f) && (y0f + 1.0f <= (float)(HF - 1));
        int yi0 = (int)fminf(fmaxf(y0f, 0.0f), (float)(HF - 1));
        int yi1 = (int)fminf(fmaxf(y0f + 1.0f, 0.0f), (float)(HF - 1));
        ys_l[2 * tid] = yi0; ys_l[2 * tid + 1] = yi1;
        ry_l[tid][0] = yi0;  ry_l[tid][1] = yi1;
        wyf[tid][0] = wy0v * (vy0 ? 1.0f : 0.0f);
        wyf[tid][1] = wy1v * (vy1 ? 1.0f : 0.0f);
    }
    __syncthreads();

    // ---- Phase B: sort+dedup (14 elems; two threads in different waves) ----
    if (tid == 0) {
        for (int a = 1; a < 14; ++a) { int v = xs_l[a]; int p2 = a;
            while (p2 > 0 && xs_l[p2 - 1] > v) { xs_l[p2] = xs_l[p2 - 1]; --p2; }
            xs_l[p2] = v; }
        int m = 1;
        for (int a = 1; a < 14; ++a) if (xs_l[a] != xs_l[m - 1]) xs_l[m++] = xs_l[a];
        s_nx = m;
    }
    if (tid == 64) {
        for (int a = 1; a < 14; ++a) { int v = ys_l[a]; int p2 = a;
            while (p2 > 0 && ys_l[p2 - 1] > v) { ys_l[p2] = ys_l[p2 - 1]; --p2; }
            ys_l[p2] = v; }
        int m = 1;
        for (int a = 1; a < 14; ++a) if (ys_l[a] != ys_l[m - 1]) ys_l[m++] = ys_l[a];
        s_ny = m;
    }
    __syncthreads();
    const int nx = s_nx, ny = s_ny;
    const int nc = nx * ny;

    // ---- Phase C: value -> list-index; cell global offsets ----
    if (tid < 7) {
#pragma unroll
        for (int d = 0; d < 2; ++d) {
            int v = rx_l[tid][d]; int idx = 0;
            for (int a = 0; a < nx; ++a) if (xs_l[a] == v) idx = a;
            rx_l[tid][d] = idx;
            v = ry_l[tid][d]; idx = 0;
            for (int a = 0; a < ny; ++a) if (ys_l[a] == v) idx = a;
            ry_l[tid][d] = idx;
        }
    }
    for (int k = tid; k < nc; k += 256) {
        int ky = k / nx, kx = k - ky * nx;
        cell_off4[k] = (ys_l[ky] * WF + xs_l[kx]) * (CC / 4);
    }
    __syncthreads();

    // ---- Phase D: per-sample quads ----
    if (tid < NS) {
        int i = tid / 7, j = tid - i * 7;
        int r0 = ry_l[i][0] * nx, r1 = ry_l[i][1] * nx;
        int c0i = rx_l[j][0], c1i = rx_l[j][1];
        s_kq[tid] = make_int4(r0 + c0i, r0 + c1i, r1 + c0i, r1 + c1i);
        float wx0 = wxf[j][0], wx1 = wxf[j][1];
        float wy0 = wyf[i][0], wy1 = wyf[i][1];
        s_wt[tid] = make_float4(wx0 * wy0, wx1 * wy0, wx0 * wy1, wx1 * wy1);
    }
    __syncthreads();

    const size_t outbase = (size_t)b * (CC * NS);
    const float4* src4   = (const float4*)src;
    const int iters = (nc + 31) >> 5;   // 32 cells staged per block-iteration

    for (int cc = 0; cc < CC / CH; ++cc) {       // 16 passes of 32 channels
        const int c04 = cc << 3;                 // chunk offset in float4s
        // ---- stage distinct cells: 8 lanes x 16B = 128B per cell ----
        for (int it = 0; it < iters; ++it) {
            int k = (it << 5) + (tid >> 3);
            if (k < nc) {
                int p = tid & 7;
                float4 v = src4[cell_off4[k] + c04 + p];
                *(float4*)&cell_lds[k * CSTR + (p << 2)] = v;
            }
        }
        __syncthreads();
        // ---- fused compute + coalesced NT store ----
        float* outc = out + outbase + (size_t)(cc * CH) * NS;
        for (int k4 = tid; k4 < NP4; k4 += 256) {
            int e = k4 << 2;
            int c = e / NS;          // compiler magic-mul
            int s = e - c * NS;
            floatv4 v;
            {
                int4 qd = s_kq[s]; float4 w = s_wt[s];
                v.x = cell_lds[qd.x * CSTR + c] * w.x + cell_lds[qd.y * CSTR + c] * w.y
                    + cell_lds[qd.z * CSTR + c] * w.z + cell_lds[qd.w * CSTR + c] * w.w;
            }
            if (++s == NS) { s = 0; ++c; }
            {
                int4 qd = s_kq[s]; float4 w = s_wt[s];
                v.y = cell_lds[qd.x * CSTR + c] * w.x + cell_lds[qd.y * CSTR + c] * w.y
                    + cell_lds[qd.z * CSTR + c] * w.z + cell_lds[qd.w * CSTR + c] * w.w;
            }
            if (++s == NS) { s = 0; ++c; }
            {
                int4 qd = s_kq[s]; float4 w = s_wt[s];
                v.z = cell_lds[qd.x * CSTR + c] * w.x + cell_lds[qd.y * CSTR + c] * w.y
                    + cell_lds[qd.z * CSTR + c] * w.z + cell_lds[qd.w * CSTR + c] * w.w;
            }
            if (++s == NS) { s = 0; ++c; }
            {
                int4 qd = s_kq[s]; float4 w = s_wt[s];
                v.w = cell_lds[qd.x * CSTR + c] * w.x + cell_lds[qd.y * CSTR + c] * w.y
                    + cell_lds[qd.z * CSTR + c] * w.z + cell_lds[qd.w * CSTR + c] * w.w;
            }
            __builtin_nontemporal_store(v, (floatv4*)outc + k4);
        }
        __syncthreads();
    }
}

// Fallback (ws too small for transpose): original scalar path on raw feats.
__global__ __launch_bounds__(256) void roi_pool_fb(const float* __restrict__ src,
                                                   const float* __restrict__ boxes,
                                                   const int* __restrict__ ih_p,
                                                   const int* __restrict__ iw_p,
                                                   float* __restrict__ out) {
    __shared__ int4   s_off[NS];
    __shared__ float4 s_wt[NS];
    __shared__ float  tile[NS * 257];

    const int b   = blockIdx.x;
    const int tid = threadIdx.x;

    if (tid < NS) {
        int4 o; float4 w4;
        box_setup(tid, b, boxes, ih_p, iw_p, &o, &w4);
        s_off[tid] = o;
        s_wt[tid]  = w4;
    }
    __syncthreads();

    const size_t outbase = (size_t)b * (CC * NS);
    for (int c0 = 0; c0 < CC; c0 += 256) {
        const int cterm = (c0 + tid) * (HF * WF);
        for (int s = 0; s < NS; ++s) {
            int4   o = s_off[s];
            float4 w = s_wt[s];
            float v = src[o.x + cterm] * w.x + src[o.y + cterm] * w.y +
                      src[o.z + cterm] * w.z + src[o.w + cterm] * w.w;
            tile[s * 257 + tid] = v;
        }
        __syncthreads();
        const size_t ob = outbase + (size_t)c0 * NS;
        for (int k = tid; k < 256 * NS; k += 256) {
            int cl = k / NS;
            int s  = k - cl * NS;
            out[ob + k] = tile[s * 257 + cl];
        }
        __syncthreads();
    }
}

extern "C" void kernel_launch(void* const* d_in, const int* in_sizes, int n_in,
                              void* d_out, int out_size, void* d_ws, size_t ws_size,
                              hipStream_t stream) {
    const float* feats = (const float*)d_in[0];
    const float* boxes = (const float*)d_in[1];
    const int*   ih    = (const int*)d_in[2];
    const int*   iw    = (const int*)d_in[3];
    float*       out   = (float*)d_out;
    const int B = in_sizes[1] / 4;

    const size_t tf_bytes = (size_t)CC * HF * WF * sizeof(float);  // 32 MiB
    const size_t need = tf_bytes + (size_t)B * sizeof(int);
    if (ws_size >= need) {
        float* tf   = (float*)d_ws;
        int*   perm = (int*)((char*)d_ws + tf_bytes);
        dim3 tb(32, 8);
        dim3 tg((HF * WF) / 32, CC / 32);
        transpose_feats<<<tg, tb, 0, stream>>>(feats, tf);
        sort_boxes<<<1, 256, 0, stream>>>(boxes, ih, iw, B, perm);
        roi_pool_v5<<<B, 256, 0, stream>>>(tf, boxes, ih, iw, perm, out);
    } else {
        roi_pool_fb<<<B, 256, 0, stream>>>(feats, boxes, ih, iw, out);
    }
}

// Round 4
// 632.045 us; speedup vs baseline: 1.0844x; 1.0844x over previous
//
#include <hip/hip_runtime.h>
#include <math.h>

#define HH 7
#define WW 7
#define CC 512
#define HF 64
#define WF 256
#define NS 49            // HH*WW
#define MAXC 196         // max distinct cells = 14 x 14
#define CSTR 40          // cell LDS stride in floats (16B-aligned; reads are consecutive-c)
#define CH 32            // channels per pass
#define NP4 ((CH * NS) / 4)   // 392 float4 outputs per pass
#define NBINS 2048       // 32 y-bands x 64 x-bins (serpentine)

typedef float floatv4 __attribute__((ext_vector_type(4)));  // native vec for NT store

// Transpose feats (C, HF*WF) -> ws (HF*WF, C) so channel gathers coalesce.
__global__ __launch_bounds__(256) void transpose_feats(const float* __restrict__ in,
                                                       float* __restrict__ out) {
    __shared__ float tile[32][33];
    const int P = HF * WF;  // 16384
    int p  = blockIdx.x * 32 + threadIdx.x;  // spatial index
    int cb = blockIdx.y * 32;                // channel base
#pragma unroll
    for (int r = 0; r < 32; r += 8)
        tile[threadIdx.y + r][threadIdx.x] = in[(size_t)(cb + threadIdx.y + r) * P + p];
    __syncthreads();
    int c  = cb + threadIdx.x;
    int pb = blockIdx.x * 32;
#pragma unroll
    for (int r = 0; r < 32; r += 8)
        out[(size_t)(pb + threadIdx.y + r) * CC + c] = tile[threadIdx.x][threadIdx.y + r];
}

// Spatial bin key: serpentine over (y-band, x-bin).
__device__ __forceinline__ int box_key(const float* __restrict__ boxes, int b,
                                       float sy, float sx) {
    float xc = boxes[b * 4 + 0];
    float yc = boxes[b * 4 + 1];
    int yb = (int)(yc * sy);
    int xb = (int)(xc * sx);
    yb = min(max(yb, 0), 31);
    xb = min(max(xb, 0), 63);
    if (yb & 1) xb = 63 - xb;          // serpentine
    return (yb << 6) | xb;
}

// Single-block counting sort of boxes by spatial bin -> perm (rank -> box id).
__global__ __launch_bounds__(256) void sort_boxes(const float* __restrict__ boxes,
                                                  const int* __restrict__ ih_p,
                                                  const int* __restrict__ iw_p,
                                                  int B, int* __restrict__ perm) {
    __shared__ int hist[NBINS];
    __shared__ int part[256];
    const int tid = threadIdx.x;
    const float sy = 32.0f / (float)ih_p[0];
    const float sx = 64.0f / (float)iw_p[0];

    for (int i = tid; i < NBINS; i += 256) hist[i] = 0;
    __syncthreads();
    for (int b = tid; b < B; b += 256)
        atomicAdd(&hist[box_key(boxes, b, sy, sx)], 1);
    __syncthreads();
    const int base = tid * (NBINS / 256);
    int s = 0;
#pragma unroll
    for (int i = 0; i < NBINS / 256; ++i) { int v = hist[base + i]; hist[base + i] = s; s += v; }
    part[tid] = s;
    __syncthreads();
    for (int d = 1; d < 256; d <<= 1) {
        int v = (tid >= d) ? part[tid - d] : 0;
        __syncthreads();
        part[tid] += v;
        __syncthreads();
    }
    const int off = part[tid] - s;   // exclusive prefix of this thread's total
#pragma unroll
    for (int i = 0; i < NBINS / 256; ++i) hist[base + i] += off;
    __syncthreads();
    for (int b = tid; b < B; b += 256) {
        int pos = atomicAdd(&hist[box_key(boxes, b, sy, sx)], 1);
        perm[pos] = b;
    }
}

// box_setup kept for the fallback path.
__device__ __forceinline__ void box_setup(int s, int b,
                                          const float* __restrict__ boxes,
                                          const int* __restrict__ ih_p,
                                          const int* __restrict__ iw_p,
                                          int4* o_out, float4* w_out) {
    int i = s / WW;
    int j = s - i * WW;
    float IW1 = (float)(iw_p[0] - 1);
    float IH1 = (float)(ih_p[0] - 1);
    float xc = boxes[b * 4 + 0];
    float yc = boxes[b * 4 + 1];
    float bw = boxes[b * 4 + 2];
    float bh = boxes[b * 4 + 3];
    float inv_w = 1.0f / IW1;
    float inv_h = 1.0f / IH1;
    float tx = (float)(j - 3) * (1.0f / 3.0f);
    float ty = (float)(i - 3) * (1.0f / 3.0f);
    float gx = (2.0f * xc - IW1) * inv_w + (bw * inv_w) * tx;
    float gy = (2.0f * yc - IH1) * inv_h + (bh * inv_h) * ty;
    float px = (gx + 1.0f) * 0.5f * (float)(WF - 1);
    float py = (gy + 1.0f) * 0.5f * (float)(HF - 1);

    float x0f = floorf(px), y0f = floorf(py);
    float wx1 = px - x0f, wx0 = 1.0f - wx1;
    float wy1 = py - y0f, wy0 = 1.0f - wy1;
    float x1f = x0f + 1.0f, y1f = y0f + 1.0f;

    bool vx0 = (x0f >= 0.0f) && (x0f <= (float)(WF - 1));
    bool vx1 = (x1f >= 0.0f) && (x1f <= (float)(WF - 1));
    bool vy0 = (y0f >= 0.0f) && (y0f <= (float)(HF - 1));
    bool vy1 = (y1f >= 0.0f) && (y1f <= (float)(HF - 1));

    int xi0 = (int)fminf(fmaxf(x0f, 0.0f), (float)(WF - 1));
    int xi1 = (int)fminf(fmaxf(x1f, 0.0f), (float)(WF - 1));
    int yi0 = (int)fminf(fmaxf(y0f, 0.0f), (float)(HF - 1));
    int yi1 = (int)fminf(fmaxf(y1f, 0.0f), (float)(HF - 1));

    int4 o;
    o.x = yi0 * WF + xi0;
    o.y = yi0 * WF + xi1;
    o.z = yi1 * WF + xi0;
    o.w = yi1 * WF + xi1;
    float4 w4;
    w4.x = wx0 * wy0 * ((vx0 && vy0) ? 1.0f : 0.0f);
    w4.y = wx1 * wy0 * ((vx1 && vy0) ? 1.0f : 0.0f);
    w4.z = wx0 * wy1 * ((vx0 && vy1) ? 1.0f : 0.0f);
    w4.w = wx1 * wy1 * ((vx1 && vy1) ? 1.0f : 0.0f);
    *o_out = o;
    *w_out = w4;
}

// One block per box (via perm + bijective XCD chunking). src = transposed feats.
// Dedup: needed cells = {distinct y corners} x {distinct x corners}.
// Per 32-channel pass: stage nc distinct cells -> LDS; compute per-sample into a
// sigma-XOR out-tile (broadcast cell reads: 8 lanes x consecutive-c = all 32
// banks once -> conflict-free despite data-dependent cell index); NT-store the
// tile (R1-verified conflict-free pattern), overlapped with next pass staging.
__global__ __launch_bounds__(256) void roi_pool_v6(const float* __restrict__ src,
                                                   const float* __restrict__ boxes,
                                                   const int* __restrict__ ih_p,
                                                   const int* __restrict__ iw_p,
                                                   const int* __restrict__ perm,
                                                   float* __restrict__ out) {
    __shared__ int    xs_l[14], ys_l[14];       // sorted-distinct corner coords
    __shared__ int    rx_l[7][2], ry_l[7][2];   // per-j / per-i: value -> index
    __shared__ float  wxf[7][2], wyf[7][2];     // validity-folded 1D weights
    __shared__ int    s_nx, s_ny;
    __shared__ int    cell_off4[MAXC];          // float4 offset of cell row in src
    __shared__ int4   s_kq[NS];                 // per-sample cell-index quad
    __shared__ float4 s_wt[NS];                 // per-sample weight quad
    __shared__ float  cell_lds[MAXC * CSTR];    // staged cells, 30.6 KB
    __shared__ float  tile[CH * 64];            // sigma-XOR out-tile, 8 KB

    const int nwg  = gridDim.x;
    const int bid  = blockIdx.x;
    const int q    = nwg >> 3, r = nwg & 7;
    const int xcd  = bid & 7, slot = bid >> 3;
    const int rank = xcd * q + min(xcd, r) + slot;
    const int b    = perm[rank];
    const int tid  = threadIdx.x;

    // ---- Phase A: corner candidates + folded 1D weights ----
    if (tid < 7) {
        float IW1 = (float)(iw_p[0] - 1);
        float IH1 = (float)(ih_p[0] - 1);
        float xc = boxes[b * 4 + 0], yc = boxes[b * 4 + 1];
        float bw = boxes[b * 4 + 2], bh = boxes[b * 4 + 3];
        float t  = (float)(tid - 3) * (1.0f / 3.0f);

        float gx  = (2.0f * xc - IW1) / IW1 + (bw / IW1) * t;
        float px  = (gx + 1.0f) * 0.5f * (float)(WF - 1);
        float x0f = floorf(px);
        float wx1 = px - x0f, wx0 = 1.0f - wx1;
        bool vx0 = (x0f >= 0.0f) && (x0f <= (float)(WF - 1));
        bool vx1 = (x0f + 1.0f >= 0.0f) && (x0f + 1.0f <= (float)(WF - 1));
        int xi0 = (int)fminf(fmaxf(x0f, 0.0f), (float)(WF - 1));
        int xi1 = (int)fminf(fmaxf(x0f + 1.0f, 0.0f), (float)(WF - 1));
        xs_l[2 * tid] = xi0; xs_l[2 * tid + 1] = xi1;
        rx_l[tid][0] = xi0;  rx_l[tid][1] = xi1;        // values (for now)
        wxf[tid][0] = wx0 * (vx0 ? 1.0f : 0.0f);
        wxf[tid][1] = wx1 * (vx1 ? 1.0f : 0.0f);

        float gy  = (2.0f * yc - IH1) / IH1 + (bh / IH1) * t;
        float py  = (gy + 1.0f) * 0.5f * (float)(HF - 1);
        float y0f = floorf(py);
        float wy1v = py - y0f, wy0v = 1.0f - wy1v;
        bool vy0 = (y0f >= 0.0f) && (y0f <= (float)(HF - 1));
        bool vy1 = (y0f + 1.0f >= 0.0f) && (y0f + 1.0f <= (float)(HF - 1));
        int yi0 = (int)fminf(fmaxf(y0f, 0.0f), (float)(HF - 1));
        int yi1 = (int)fminf(fmaxf(y0f + 1.0f, 0.0f), (float)(HF - 1));
        ys_l[2 * tid] = yi0; ys_l[2 * tid + 1] = yi1;
        ry_l[tid][0] = yi0;  ry_l[tid][1] = yi1;
        wyf[tid][0] = wy0v * (vy0 ? 1.0f : 0.0f);
        wyf[tid][1] = wy1v * (vy1 ? 1.0f : 0.0f);
    }
    __syncthreads();

    // ---- Phase B: sort+dedup (14 elems; two threads in different waves) ----
    if (tid == 0) {
        for (int a = 1; a < 14; ++a) { int v = xs_l[a]; int p2 = a;
            while (p2 > 0 && xs_l[p2 - 1] > v) { xs_l[p2] = xs_l[p2 - 1]; --p2; }
            xs_l[p2] = v; }
        int m = 1;
        for (int a = 1; a < 14; ++a) if (xs_l[a] != xs_l[m - 1]) xs_l[m++] = xs_l[a];
        s_nx = m;
    }
    if (tid == 64) {
        for (int a = 1; a < 14; ++a) { int v = ys_l[a]; int p2 = a;
            while (p2 > 0 && ys_l[p2 - 1] > v) { ys_l[p2] = ys_l[p2 - 1]; --p2; }
            ys_l[p2] = v; }
        int m = 1;
        for (int a = 1; a < 14; ++a) if (ys_l[a] != ys_l[m - 1]) ys_l[m++] = ys_l[a];
        s_ny = m;
    }
    __syncthreads();
    const int nx = s_nx, ny = s_ny;
    const int nc = nx * ny;

    // ---- Phase C: value -> list-index; cell global offsets ----
    if (tid < 7) {
#pragma unroll
        for (int d = 0; d < 2; ++d) {
            int v = rx_l[tid][d]; int idx = 0;
            for (int a = 0; a < nx; ++a) if (xs_l[a] == v) idx = a;
            rx_l[tid][d] = idx;
            v = ry_l[tid][d]; idx = 0;
            for (int a = 0; a < ny; ++a) if (ys_l[a] == v) idx = a;
            ry_l[tid][d] = idx;
        }
    }
    for (int k = tid; k < nc; k += 256) {
        int ky = k / nx, kx = k - ky * nx;
        cell_off4[k] = (ys_l[ky] * WF + xs_l[kx]) * (CC / 4);
    }
    __syncthreads();

    // ---- Phase D: per-sample quads ----
    if (tid < NS) {
        int i = tid / 7, j = tid - i * 7;
        int r0 = ry_l[i][0] * nx, r1 = ry_l[i][1] * nx;
        int c0i = rx_l[j][0], c1i = rx_l[j][1];
        s_kq[tid] = make_int4(r0 + c0i, r0 + c1i, r1 + c0i, r1 + c1i);
        float wx0 = wxf[j][0], wx1 = wxf[j][1];
        float wy0 = wyf[i][0], wy1 = wyf[i][1];
        s_wt[tid] = make_float4(wx0 * wy0, wx1 * wy0, wx0 * wy1, wx1 * wy1);
    }
    __syncthreads();

    const size_t outbase = (size_t)b * (CC * NS);
    const float4* src4   = (const float4*)src;
    const int iters = (nc + 31) >> 5;   // 32 cells staged per block-iteration
    const int g8  = tid & 7;            // float4 channel-group (4 channels)
    const int h32 = tid >> 3;           // sample 0..31

    // stage cells for pass cc: 8 lanes x 16B = 128B per cell
#define STAGE(cc_)                                                         \
    do {                                                                   \
        int c04_ = (cc_) << 3;                                             \
        for (int it = 0; it < iters; ++it) {                               \
            int k = (it << 5) + (tid >> 3);                                \
            if (k < nc) {                                                  \
                int p = tid & 7;                                           \
                float4 v = src4[cell_off4[k] + c04_ + p];                  \
                *(float4*)&cell_lds[k * CSTR + (p << 2)] = v;              \
            }                                                              \
        }                                                                  \
    } while (0)

    STAGE(0);
    __syncthreads();

    for (int cc = 0; cc < CC / CH; ++cc) {       // 16 passes of 32 channels
        // ---- compute: sample h32 (+32), 8 lanes x consecutive-c cell reads ----
#pragma unroll
        for (int half = 0; half < 2; ++half) {
            int s = h32 + (half << 5);
            if (s < NS) {
                int4   qd = s_kq[s];
                float4 w  = s_wt[s];
                int go = g8 << 2;
                float4 a  = *(const float4*)&cell_lds[qd.x * CSTR + go];
                float4 b4 = *(const float4*)&cell_lds[qd.y * CSTR + go];
                float4 c4 = *(const float4*)&cell_lds[qd.z * CSTR + go];
                float4 d4 = *(const float4*)&cell_lds[qd.w * CSTR + go];
                float4 v;
                v.x = a.x * w.x + b4.x * w.y + c4.x * w.z + d4.x * w.w;
                v.y = a.y * w.x + b4.y * w.y + c4.y * w.z + d4.y * w.w;
                v.z = a.z * w.x + b4.z * w.y + c4.z * w.z + d4.z * w.w;
                v.w = a.w * w.x + b4.w * w.y + c4.w * w.z + d4.w * w.w;
                int sig  = (s >> 2) | ((s & 3) << 4);
                int sw   = sig ^ g8;
                int base = g8 << 8;                  // (4*g8)*64
                tile[base +       sw] = v.x;
                tile[base +  64 + sw] = v.y;
                tile[base + 128 + sw] = v.z;
                tile[base + 192 + sw] = v.w;
            }
        }
        __syncthreads();
        // ---- write tile (NT, coalesced) overlapped with next pass staging ----
        float* outc = out + outbase + (size_t)(cc * CH) * NS;
        for (int k4 = tid; k4 < NP4; k4 += 256) {
            int e = k4 << 2;
            int c = e / NS;          // compiler magic-mul
            int s = e - c * NS;
            floatv4 v;
            v.x = tile[(c << 6) + (((s >> 2) | ((s & 3) << 4)) ^ (c >> 2))];
            if (++s == NS) { s = 0; ++c; }
            v.y = tile[(c << 6) + (((s >> 2) | ((s & 3) << 4)) ^ (c >> 2))];
            if (++s == NS) { s = 0; ++c; }
            v.z = tile[(c << 6) + (((s >> 2) | ((s & 3) << 4)) ^ (c >> 2))];
            if (++s == NS) { s = 0; ++c; }
            v.w = tile[(c << 6) + (((s >> 2) | ((s & 3) << 4)) ^ (c >> 2))];
            __builtin_nontemporal_store(v, (floatv4*)outc + k4);
        }
        if (cc + 1 < CC / CH) STAGE(cc + 1);   // overlaps with NT stores
        __syncthreads();
    }
#undef STAGE
}

// Fallback (ws too small for transpose): original scalar path on raw feats.
__global__ __launch_bounds__(256) void roi_pool_fb(const float* __restrict__ src,
                                                   const float* __restrict__ boxes,
                                                   const int* __restrict__ ih_p,
                                                   const int* __restrict__ iw_p,
                                                   float* __restrict__ out) {
    __shared__ int4   s_off[NS];
    __shared__ float4 s_wt[NS];
    __shared__ float  tile[NS * 257];

    const int b   = blockIdx.x;
    const int tid = threadIdx.x;

    if (tid < NS) {
        int4 o; float4 w4;
        box_setup(tid, b, boxes, ih_p, iw_p, &o, &w4);
        s_off[tid] = o;
        s_wt[tid]  = w4;
    }
    __syncthreads();

    const size_t outbase = (size_t)b * (CC * NS);
    for (int c0 = 0; c0 < CC; c0 += 256) {
        const int cterm = (c0 + tid) * (HF * WF);
        for (int s = 0; s < NS; ++s) {
            int4   o = s_off[s];
            float4 w = s_wt[s];
            float v = src[o.x + cterm] * w.x + src[o.y + cterm] * w.y +
                      src[o.z + cterm] * w.z + src[o.w + cterm] * w.w;
            tile[s * 257 + tid] = v;
        }
        __syncthreads();
        const size_t ob = outbase + (size_t)c0 * NS;
        for (int k = tid; k < 256 * NS; k += 256) {
            int cl = k / NS;
            int s  = k - cl * NS;
            out[ob + k] = tile[s * 257 + cl];
        }
        __syncthreads();
    }
}

extern "C" void kernel_launch(void* const* d_in, const int* in_sizes, int n_in,
                              void* d_out, int out_size, void* d_ws, size_t ws_size,
                              hipStream_t stream) {
    const float* feats = (const float*)d_in[0];
    const float* boxes = (const float*)d_in[1];
    const int*   ih    = (const int*)d_in[2];
    const int*   iw    = (const int*)d_in[3];
    float*       out   = (float*)d_out;
    const int B = in_sizes[1] / 4;

    const size_t tf_bytes = (size_t)CC * HF * WF * sizeof(float);  // 32 MiB
    const size_t need = tf_bytes + (size_t)B * sizeof(int);
    if (ws_size >= need) {
        float* tf   = (float*)d_ws;
        int*   perm = (int*)((char*)d_ws + tf_bytes);
        dim3 tb(32, 8);
        dim3 tg((HF * WF) / 32, CC / 32);
        transpose_feats<<<tg, tb, 0, stream>>>(feats, tf);
        sort_boxes<<<1, 256, 0, stream>>>(boxes, ih, iw, B, perm);
        roi_pool_v6<<<B, 256, 0, stream>>>(tf, boxes, ih, iw, perm, out);
    } else {
        roi_pool_fb<<<B, 256, 0, stream>>>(feats, boxes, ih, iw, out);
    }
}

// Round 5
// 465.144 us; speedup vs baseline: 1.4735x; 1.3588x over previous
//
#include <hip/hip_runtime.h>
#include <math.h>

#define HH 7
#define WW 7
#define CC 512
#define HF 64
#define WF 256
#define NS 49            // HH*WW
#define CHUNK 128        // channels per tile pass
#define ROWS4 (CC / 4)   // float4 elements per spatial row of transposed feats
#define NE4 ((CHUNK * NS) / 4)   // 1568 float4 outputs per chunk
#define NBINS 2048       // 32 y-bands x 64 x-bins (serpentine)

typedef float floatv4 __attribute__((ext_vector_type(4)));  // native vec for NT store

// Transpose feats (C, HF*WF) -> ws (HF*WF, C) so channel gathers coalesce.
__global__ __launch_bounds__(256) void transpose_feats(const float* __restrict__ in,
                                                       float* __restrict__ out) {
    __shared__ float tile[32][33];
    const int P = HF * WF;  // 16384
    int p  = blockIdx.x * 32 + threadIdx.x;  // spatial index
    int cb = blockIdx.y * 32;                // channel base
#pragma unroll
    for (int r = 0; r < 32; r += 8)
        tile[threadIdx.y + r][threadIdx.x] = in[(size_t)(cb + threadIdx.y + r) * P + p];
    __syncthreads();
    int c  = cb + threadIdx.x;
    int pb = blockIdx.x * 32;
#pragma unroll
    for (int r = 0; r < 32; r += 8)
        out[(size_t)(pb + threadIdx.y + r) * CC + c] = tile[threadIdx.x][threadIdx.y + r];
}

// Spatial bin key: serpentine over (y-band, x-bin).
__device__ __forceinline__ int box_key(const float* __restrict__ boxes, int b,
                                       float sy, float sx) {
    float xc = boxes[b * 4 + 0];
    float yc = boxes[b * 4 + 1];
    int yb = (int)(yc * sy);
    int xb = (int)(xc * sx);
    yb = min(max(yb, 0), 31);
    xb = min(max(xb, 0), 63);
    if (yb & 1) xb = 63 - xb;          // serpentine
    return (yb << 6) | xb;
}

// ---- Parallel permutation build (replaces the single-block sort: ~80us -> ~10us) ----
__global__ __launch_bounds__(256) void hist_zero(int* __restrict__ hist) {
    hist[blockIdx.x * 256 + threadIdx.x] = 0;
}

__global__ __launch_bounds__(256) void hist_count(const float* __restrict__ boxes,
                                                  const int* __restrict__ ih_p,
                                                  const int* __restrict__ iw_p,
                                                  int B, int* __restrict__ hist) {
    int b = blockIdx.x * 256 + threadIdx.x;
    if (b < B) {
        float sy = 32.0f / (float)ih_p[0];
        float sx = 64.0f / (float)iw_p[0];
        atomicAdd(&hist[box_key(boxes, b, sy, sx)], 1);   // device-scope by default
    }
}

// Exclusive prefix sum over NBINS global ints (1 block, 2048 elems: fast).
__global__ __launch_bounds__(256) void hist_scan(int* __restrict__ hist) {
    __shared__ int part[256];
    const int tid  = threadIdx.x;
    const int base = tid * (NBINS / 256);
    int v[NBINS / 256];
    int s = 0;
#pragma unroll
    for (int i = 0; i < NBINS / 256; ++i) { v[i] = s; s += hist[base + i]; }
    part[tid] = s;
    __syncthreads();
    for (int d = 1; d < 256; d <<= 1) {
        int t = (tid >= d) ? part[tid - d] : 0;
        __syncthreads();
        part[tid] += t;
        __syncthreads();
    }
    const int off = part[tid] - s;   // exclusive prefix of this thread's total
#pragma unroll
    for (int i = 0; i < NBINS / 256; ++i) hist[base + i] = v[i] + off;
}

__global__ __launch_bounds__(256) void scatter_perm(const float* __restrict__ boxes,
                                                    const int* __restrict__ ih_p,
                                                    const int* __restrict__ iw_p,
                                                    int B, int* __restrict__ hist,
                                                    int* __restrict__ perm) {
    int b = blockIdx.x * 256 + threadIdx.x;
    if (b < B) {
        float sy = 32.0f / (float)ih_p[0];
        float sx = 64.0f / (float)iw_p[0];
        int pos = atomicAdd(&hist[box_key(boxes, b, sy, sx)], 1);
        perm[pos] = b;
    }
}

__device__ __forceinline__ void box_setup(int s, int b,
                                          const float* __restrict__ boxes,
                                          const int* __restrict__ ih_p,
                                          const int* __restrict__ iw_p,
                                          int4* o_out, float4* w_out) {
    int i = s / WW;
    int j = s - i * WW;
    float IW1 = (float)(iw_p[0] - 1);
    float IH1 = (float)(ih_p[0] - 1);
    float xc = boxes[b * 4 + 0];
    float yc = boxes[b * 4 + 1];
    float bw = boxes[b * 4 + 2];
    float bh = boxes[b * 4 + 3];
    float inv_w = 1.0f / IW1;
    float inv_h = 1.0f / IH1;
    float tx = (float)(j - 3) * (1.0f / 3.0f);
    float ty = (float)(i - 3) * (1.0f / 3.0f);
    float gx = (2.0f * xc - IW1) * inv_w + (bw * inv_w) * tx;
    float gy = (2.0f * yc - IH1) * inv_h + (bh * inv_h) * ty;
    float px = (gx + 1.0f) * 0.5f * (float)(WF - 1);
    float py = (gy + 1.0f) * 0.5f * (float)(HF - 1);

    float x0f = floorf(px), y0f = floorf(py);
    float wx1 = px - x0f, wx0 = 1.0f - wx1;
    float wy1 = py - y0f, wy0 = 1.0f - wy1;
    float x1f = x0f + 1.0f, y1f = y0f + 1.0f;

    bool vx0 = (x0f >= 0.0f) && (x0f <= (float)(WF - 1));
    bool vx1 = (x1f >= 0.0f) && (x1f <= (float)(WF - 1));
    bool vy0 = (y0f >= 0.0f) && (y0f <= (float)(HF - 1));
    bool vy1 = (y1f >= 0.0f) && (y1f <= (float)(HF - 1));

    int xi0 = (int)fminf(fmaxf(x0f, 0.0f), (float)(WF - 1));
    int xi1 = (int)fminf(fmaxf(x1f, 0.0f), (float)(WF - 1));
    int yi0 = (int)fminf(fmaxf(y0f, 0.0f), (float)(HF - 1));
    int yi1 = (int)fminf(fmaxf(y1f, 0.0f), (float)(HF - 1));

    int4 o;
    o.x = yi0 * WF + xi0;
    o.y = yi0 * WF + xi1;
    o.z = yi1 * WF + xi0;
    o.w = yi1 * WF + xi1;
    float4 w4;
    w4.x = wx0 * wy0 * ((vx0 && vy0) ? 1.0f : 0.0f);
    w4.y = wx1 * wy0 * ((vx1 && vy0) ? 1.0f : 0.0f);
    w4.z = wx0 * wy1 * ((vx0 && vy1) ? 1.0f : 0.0f);
    w4.w = wx1 * wy1 * ((vx1 && vy1) ? 1.0f : 0.0f);
    *o_out = o;
    *w_out = w4;
}

// One block per box (via perm + bijective XCD chunking). src is transposed
// feats: (HF*WF, CC), channel-contiguous. Measured best structure (R2, 0 LDS conflicts).
// LDS layout: addr(s,c) = c*64 + (sigma(s) ^ (c>>2)),  sigma(s) = (s>>2)|((s&3)<<4).
__global__ __launch_bounds__(256) void roi_pool_v4(const float* __restrict__ src,
                                                   const float* __restrict__ boxes,
                                                   const int* __restrict__ ih_p,
                                                   const int* __restrict__ iw_p,
                                                   const int* __restrict__ perm,
                                                   float* __restrict__ out) {
    __shared__ int4   s_off[NS];   // float4-row base: cell*ROWS4
    __shared__ float4 s_wt[NS];
    __shared__ float  tile[CHUNK * 64];  // 32 KB, XOR-swizzled

    const int nwg  = gridDim.x;
    const int bid  = blockIdx.x;
    const int q    = nwg >> 3, r = nwg & 7;
    const int xcd  = bid & 7, slot = bid >> 3;
    const int rank = xcd * q + min(xcd, r) + slot;
    const int b    = perm[rank];

    const int tid = threadIdx.x;
    const int g   = tid & 31;   // float4 channel-group within 128-chunk (c>>2)
    const int h   = tid >> 5;   // sample phase 0..7

    if (tid < NS) {
        int4 o; float4 w4;
        box_setup(tid, b, boxes, ih_p, iw_p, &o, &w4);
        o.x *= ROWS4; o.y *= ROWS4; o.z *= ROWS4; o.w *= ROWS4;
        s_off[tid] = o;
        s_wt[tid]  = w4;
    }
    __syncthreads();

    // Hoist per-sample constants into registers (static unroll -> stays in VGPRs).
    int4   o_r[7];
    float4 w_r[7];
    int    sig_r[7];
#pragma unroll
    for (int it = 0; it < 7; ++it) {
        int s = h + (it << 3);
        if (s < NS) {
            o_r[it]   = s_off[s];
            w_r[it]   = s_wt[s];
            sig_r[it] = (s >> 2) | ((s & 3) << 4);
        }
    }

    const size_t outbase = (size_t)b * (CC * NS);
    const float4* src4   = (const float4*)src;

    for (int c0 = 0; c0 < CC; c0 += CHUNK) {
        const int cb4 = c0 >> 2;
        // ---- compute phase: half-wave = one sample, lane = 4-channel group ----
#pragma unroll
        for (int it = 0; it < 7; ++it) {
            int s = h + (it << 3);
            if (s < NS) {
                int4   o = o_r[it];
                float4 w = w_r[it];
                float4 a  = src4[o.x + cb4 + g];
                float4 bb = src4[o.y + cb4 + g];
                float4 c  = src4[o.z + cb4 + g];
                float4 d  = src4[o.w + cb4 + g];
                int base = g << 8;              // c_local=4g -> c*64
                int sw   = sig_r[it] ^ g;
                tile[base +       sw] = a.x * w.x + bb.x * w.y + c.x * w.z + d.x * w.w;
                tile[base +  64 + sw] = a.y * w.x + bb.y * w.y + c.y * w.z + d.y * w.w;
                tile[base + 128 + sw] = a.z * w.x + bb.z * w.y + c.z * w.z + d.z * w.w;
                tile[base + 192 + sw] = a.w * w.x + bb.w * w.y + c.w * w.z + d.w * w.w;
            }
        }
        __syncthreads();
        // ---- write phase: lane = output order (coalesced float4 NT stores) ----
        float* outc = out + outbase + (size_t)c0 * NS;
        for (int k4 = tid; k4 < NE4; k4 += 256) {
            int e = k4 << 2;
            int c = e / NS;          // compiler magic-mul
            int s = e - c * NS;
            floatv4 v;
            v.x = tile[(c << 6) + (((s >> 2) | ((s & 3) << 4)) ^ (c >> 2))];
            if (++s == NS) { s = 0; ++c; }
            v.y = tile[(c << 6) + (((s >> 2) | ((s & 3) << 4)) ^ (c >> 2))];
            if (++s == NS) { s = 0; ++c; }
            v.z = tile[(c << 6) + (((s >> 2) | ((s & 3) << 4)) ^ (c >> 2))];
            if (++s == NS) { s = 0; ++c; }
            v.w = tile[(c << 6) + (((s >> 2) | ((s & 3) << 4)) ^ (c >> 2))];
            __builtin_nontemporal_store(v, (floatv4*)outc + k4);
        }
        __syncthreads();
    }
}

// Fallback (ws too small for transpose): original scalar path on raw feats.
__global__ __launch_bounds__(256) void roi_pool_fb(const float* __restrict__ src,
                                                   const float* __restrict__ boxes,
                                                   const int* __restrict__ ih_p,
                                                   const int* __restrict__ iw_p,
                                                   float* __restrict__ out) {
    __shared__ int4   s_off[NS];
    __shared__ float4 s_wt[NS];
    __shared__ float  tile[NS * 257];

    const int b   = blockIdx.x;
    const int tid = threadIdx.x;

    if (tid < NS) {
        int4 o; float4 w4;
        box_setup(tid, b, boxes, ih_p, iw_p, &o, &w4);
        s_off[tid] = o;
        s_wt[tid]  = w4;
    }
    __syncthreads();

    const size_t outbase = (size_t)b * (CC * NS);
    for (int c0 = 0; c0 < CC; c0 += 256) {
        const int cterm = (c0 + tid) * (HF * WF);
        for (int s = 0; s < NS; ++s) {
            int4   o = s_off[s];
            float4 w = s_wt[s];
            float v = src[o.x + cterm] * w.x + src[o.y + cterm] * w.y +
                      src[o.z + cterm] * w.z + src[o.w + cterm] * w.w;
            tile[s * 257 + tid] = v;
        }
        __syncthreads();
        const size_t ob = outbase + (size_t)c0 * NS;
        for (int k = tid; k < 256 * NS; k += 256) {
            int cl = k / NS;
            int s  = k - cl * NS;
            out[ob + k] = tile[s * 257 + cl];
        }
        __syncthreads();
    }
}

extern "C" void kernel_launch(void* const* d_in, const int* in_sizes, int n_in,
                              void* d_out, int out_size, void* d_ws, size_t ws_size,
                              hipStream_t stream) {
    const float* feats = (const float*)d_in[0];
    const float* boxes = (const float*)d_in[1];
    const int*   ih    = (const int*)d_in[2];
    const int*   iw    = (const int*)d_in[3];
    float*       out   = (float*)d_out;
    const int B = in_sizes[1] / 4;

    const size_t tf_bytes = (size_t)CC * HF * WF * sizeof(float);  // 32 MiB
    const size_t need = tf_bytes + (size_t)B * sizeof(int) + (size_t)NBINS * sizeof(int);
    if (ws_size >= need) {
        float* tf   = (float*)d_ws;
        int*   perm = (int*)((char*)d_ws + tf_bytes);
        int*   hist = (int*)((char*)d_ws + tf_bytes + (size_t)B * sizeof(int));
        dim3 tb(32, 8);
        dim3 tg((HF * WF) / 32, CC / 32);
        transpose_feats<<<tg, tb, 0, stream>>>(feats, tf);
        hist_zero<<<NBINS / 256, 256, 0, stream>>>(hist);
        hist_count<<<(B + 255) / 256, 256, 0, stream>>>(boxes, ih, iw, B, hist);
        hist_scan<<<1, 256, 0, stream>>>(hist);
        scatter_perm<<<(B + 255) / 256, 256, 0, stream>>>(boxes, ih, iw, B, hist, perm);
        roi_pool_v4<<<B, 256, 0, stream>>>(tf, boxes, ih, iw, perm, out);
    } else {
        roi_pool_fb<<<B, 256, 0, stream>>>(feats, boxes, ih, iw, out);
    }
}

// Round 6
// 464.479 us; speedup vs baseline: 1.4756x; 1.0014x over previous
//
#include <hip/hip_runtime.h>
#include <math.h>

#define HH 7
#define WW 7
#define CC 512
#define HF 64
#define WF 256
#define NS 49            // HH*WW
#define CHUNK 64         // channels per tile pass (L1-fit: distinct cells*256B <~ 32KB)
#define ROWS4 (CC / 4)   // float4 elements per spatial row of transposed feats
#define NE4 ((CHUNK * NS) / 4)   // 784 float4 outputs per chunk
#define NBINS 2048       // 32 y-bands x 64 x-bins (serpentine)

typedef float floatv4 __attribute__((ext_vector_type(4)));  // native vec for NT store

// Transpose feats (C, HF*WF) -> ws (HF*WF, C) so channel gathers coalesce.
__global__ __launch_bounds__(256) void transpose_feats(const float* __restrict__ in,
                                                       float* __restrict__ out) {
    __shared__ float tile[32][33];
    const int P = HF * WF;  // 16384
    int p  = blockIdx.x * 32 + threadIdx.x;  // spatial index
    int cb = blockIdx.y * 32;                // channel base
#pragma unroll
    for (int r = 0; r < 32; r += 8)
        tile[threadIdx.y + r][threadIdx.x] = in[(size_t)(cb + threadIdx.y + r) * P + p];
    __syncthreads();
    int c  = cb + threadIdx.x;
    int pb = blockIdx.x * 32;
#pragma unroll
    for (int r = 0; r < 32; r += 8)
        out[(size_t)(pb + threadIdx.y + r) * CC + c] = tile[threadIdx.x][threadIdx.y + r];
}

// Spatial bin key: serpentine over (y-band, x-bin).
__device__ __forceinline__ int box_key(const float* __restrict__ boxes, int b,
                                       float sy, float sx) {
    float xc = boxes[b * 4 + 0];
    float yc = boxes[b * 4 + 1];
    int yb = (int)(yc * sy);
    int xb = (int)(xc * sx);
    yb = min(max(yb, 0), 31);
    xb = min(max(xb, 0), 63);
    if (yb & 1) xb = 63 - xb;          // serpentine
    return (yb << 6) | xb;
}

// ---- Parallel permutation build ----
__global__ __launch_bounds__(256) void hist_zero(int* __restrict__ hist) {
    hist[blockIdx.x * 256 + threadIdx.x] = 0;
}

__global__ __launch_bounds__(256) void hist_count(const float* __restrict__ boxes,
                                                  const int* __restrict__ ih_p,
                                                  const int* __restrict__ iw_p,
                                                  int B, int* __restrict__ hist) {
    int b = blockIdx.x * 256 + threadIdx.x;
    if (b < B) {
        float sy = 32.0f / (float)ih_p[0];
        float sx = 64.0f / (float)iw_p[0];
        atomicAdd(&hist[box_key(boxes, b, sy, sx)], 1);   // device-scope by default
    }
}

// Exclusive prefix sum over NBINS global ints (1 block, 2048 elems).
__global__ __launch_bounds__(256) void hist_scan(int* __restrict__ hist) {
    __shared__ int part[256];
    const int tid  = threadIdx.x;
    const int base = tid * (NBINS / 256);
    int v[NBINS / 256];
    int s = 0;
#pragma unroll
    for (int i = 0; i < NBINS / 256; ++i) { v[i] = s; s += hist[base + i]; }
    part[tid] = s;
    __syncthreads();
    for (int d = 1; d < 256; d <<= 1) {
        int t = (tid >= d) ? part[tid - d] : 0;
        __syncthreads();
        part[tid] += t;
        __syncthreads();
    }
    const int off = part[tid] - s;   // exclusive prefix of this thread's total
#pragma unroll
    for (int i = 0; i < NBINS / 256; ++i) hist[base + i] = v[i] + off;
}

__global__ __launch_bounds__(256) void scatter_perm(const float* __restrict__ boxes,
                                                    const int* __restrict__ ih_p,
                                                    const int* __restrict__ iw_p,
                                                    int B, int* __restrict__ hist,
                                                    int* __restrict__ perm) {
    int b = blockIdx.x * 256 + threadIdx.x;
    if (b < B) {
        float sy = 32.0f / (float)ih_p[0];
        float sx = 64.0f / (float)iw_p[0];
        int pos = atomicAdd(&hist[box_key(boxes, b, sy, sx)], 1);
        perm[pos] = b;
    }
}

__device__ __forceinline__ void box_setup(int s, int b,
                                          const float* __restrict__ boxes,
                                          const int* __restrict__ ih_p,
                                          const int* __restrict__ iw_p,
                                          int4* o_out, float4* w_out) {
    int i = s / WW;
    int j = s - i * WW;
    float IW1 = (float)(iw_p[0] - 1);
    float IH1 = (float)(ih_p[0] - 1);
    float xc = boxes[b * 4 + 0];
    float yc = boxes[b * 4 + 1];
    float bw = boxes[b * 4 + 2];
    float bh = boxes[b * 4 + 3];
    float inv_w = 1.0f / IW1;
    float inv_h = 1.0f / IH1;
    float tx = (float)(j - 3) * (1.0f / 3.0f);
    float ty = (float)(i - 3) * (1.0f / 3.0f);
    float gx = (2.0f * xc - IW1) * inv_w + (bw * inv_w) * tx;
    float gy = (2.0f * yc - IH1) * inv_h + (bh * inv_h) * ty;
    float px = (gx + 1.0f) * 0.5f * (float)(WF - 1);
    float py = (gy + 1.0f) * 0.5f * (float)(HF - 1);

    float x0f = floorf(px), y0f = floorf(py);
    float wx1 = px - x0f, wx0 = 1.0f - wx1;
    float wy1 = py - y0f, wy0 = 1.0f - wy1;
    float x1f = x0f + 1.0f, y1f = y0f + 1.0f;

    bool vx0 = (x0f >= 0.0f) && (x0f <= (float)(WF - 1));
    bool vx1 = (x1f >= 0.0f) && (x1f <= (float)(WF - 1));
    bool vy0 = (y0f >= 0.0f) && (y0f <= (float)(HF - 1));
    bool vy1 = (y1f >= 0.0f) && (y1f <= (float)(HF - 1));

    int xi0 = (int)fminf(fmaxf(x0f, 0.0f), (float)(WF - 1));
    int xi1 = (int)fminf(fmaxf(x1f, 0.0f), (float)(WF - 1));
    int yi0 = (int)fminf(fmaxf(y0f, 0.0f), (float)(HF - 1));
    int yi1 = (int)fminf(fmaxf(y1f, 0.0f), (float)(HF - 1));

    int4 o;
    o.x = yi0 * WF + xi0;
    o.y = yi0 * WF + xi1;
    o.z = yi1 * WF + xi0;
    o.w = yi1 * WF + xi1;
    float4 w4;
    w4.x = wx0 * wy0 * ((vx0 && vy0) ? 1.0f : 0.0f);
    w4.y = wx1 * wy0 * ((vx1 && vy0) ? 1.0f : 0.0f);
    w4.z = wx0 * wy1 * ((vx0 && vy1) ? 1.0f : 0.0f);
    w4.w = wx1 * wy1 * ((vx1 && vy1) ? 1.0f : 0.0f);
    *o_out = o;
    *w_out = w4;
}

// One block per box (via perm + bijective XCD chunking). src is transposed
// feats: (HF*WF, CC), channel-contiguous. v4 structure with CHUNK=64 so the
// per-chunk distinct-cell footprint (<=196 x 256B) fits the 32KB L1 -> duplicate
// corner reads (intra-block and sorted-neighbor inter-block) become L1 hits.
// LDS layout: addr(s,c) = c*64 + (sigma(s) ^ (c>>2)),  sigma(s) = (s>>2)|((s&3)<<4).
__global__ __launch_bounds__(256) void roi_pool_v7(const float* __restrict__ src,
                                                   const float* __restrict__ boxes,
                                                   const int* __restrict__ ih_p,
                                                   const int* __restrict__ iw_p,
                                                   const int* __restrict__ perm,
                                                   float* __restrict__ out) {
    __shared__ int4   s_off[NS];   // float4-row base: cell*ROWS4
    __shared__ float4 s_wt[NS];
    __shared__ float  tile[CHUNK * 64];  // 16 KB, XOR-swizzled

    const int nwg  = gridDim.x;
    const int bid  = blockIdx.x;
    const int q    = nwg >> 3, r = nwg & 7;
    const int xcd  = bid & 7, slot = bid >> 3;
    const int rank = xcd * q + min(xcd, r) + slot;
    const int b    = perm[rank];

    const int tid = threadIdx.x;
    const int g   = tid & 15;   // float4 channel-group within 64-chunk (c>>2)
    const int ph  = tid >> 4;   // sample phase 0..15

    if (tid < NS) {
        int4 o; float4 w4;
        box_setup(tid, b, boxes, ih_p, iw_p, &o, &w4);
        o.x *= ROWS4; o.y *= ROWS4; o.z *= ROWS4; o.w *= ROWS4;
        s_off[tid] = o;
        s_wt[tid]  = w4;
    }
    __syncthreads();

    // Hoist per-sample constants into registers (static unroll -> stays in VGPRs).
    int4   o_r[4];
    float4 w_r[4];
    int    sig_r[4];
#pragma unroll
    for (int it = 0; it < 4; ++it) {
        int s = ph + (it << 4);
        if (s < NS) {
            o_r[it]   = s_off[s];
            w_r[it]   = s_wt[s];
            sig_r[it] = (s >> 2) | ((s & 3) << 4);
        }
    }

    const size_t outbase = (size_t)b * (CC * NS);
    const float4* src4   = (const float4*)src;

    for (int c0 = 0; c0 < CC; c0 += CHUNK) {     // 8 chunks of 64 channels
        const int cb4 = c0 >> 2;
        // ---- compute phase: 16 lanes = one sample (256B slice), 16 phases ----
#pragma unroll
        for (int it = 0; it < 4; ++it) {
            int s = ph + (it << 4);
            if (s < NS) {
                int4   o = o_r[it];
                float4 w = w_r[it];
                float4 a  = src4[o.x + cb4 + g];
                float4 bb = src4[o.y + cb4 + g];
                float4 c  = src4[o.z + cb4 + g];
                float4 d  = src4[o.w + cb4 + g];
                int base = g << 8;              // c_local=4g -> c*64
                int sw   = sig_r[it] ^ g;
                tile[base +       sw] = a.x * w.x + bb.x * w.y + c.x * w.z + d.x * w.w;
                tile[base +  64 + sw] = a.y * w.x + bb.y * w.y + c.y * w.z + d.y * w.w;
                tile[base + 128 + sw] = a.z * w.x + bb.z * w.y + c.z * w.z + d.z * w.w;
                tile[base + 192 + sw] = a.w * w.x + bb.w * w.y + c.w * w.z + d.w * w.w;
            }
        }
        __syncthreads();
        // ---- write phase: lane = output order (coalesced float4 NT stores) ----
        float* outc = out + outbase + (size_t)c0 * NS;
        for (int k4 = tid; k4 < NE4; k4 += 256) {
            int e = k4 << 2;
            int c = e / NS;          // compiler magic-mul
            int s = e - c * NS;
            floatv4 v;
            v.x = tile[(c << 6) + (((s >> 2) | ((s & 3) << 4)) ^ (c >> 2))];
            if (++s == NS) { s = 0; ++c; }
            v.y = tile[(c << 6) + (((s >> 2) | ((s & 3) << 4)) ^ (c >> 2))];
            if (++s == NS) { s = 0; ++c; }
            v.z = tile[(c << 6) + (((s >> 2) | ((s & 3) << 4)) ^ (c >> 2))];
            if (++s == NS) { s = 0; ++c; }
            v.w = tile[(c << 6) + (((s >> 2) | ((s & 3) << 4)) ^ (c >> 2))];
            __builtin_nontemporal_store(v, (floatv4*)outc + k4);
        }
        __syncthreads();
    }
}

// Fallback (ws too small for transpose): original scalar path on raw feats.
__global__ __launch_bounds__(256) void roi_pool_fb(const float* __restrict__ src,
                                                   const float* __restrict__ boxes,
                                                   const int* __restrict__ ih_p,
                                                   const int* __restrict__ iw_p,
                                                   float* __restrict__ out) {
    __shared__ int4   s_off[NS];
    __shared__ float4 s_wt[NS];
    __shared__ float  tile[NS * 257];

    const int b   = blockIdx.x;
    const int tid = threadIdx.x;

    if (tid < NS) {
        int4 o; float4 w4;
        box_setup(tid, b, boxes, ih_p, iw_p, &o, &w4);
        s_off[tid] = o;
        s_wt[tid]  = w4;
    }
    __syncthreads();

    const size_t outbase = (size_t)b * (CC * NS);
    for (int c0 = 0; c0 < CC; c0 += 256) {
        const int cterm = (c0 + tid) * (HF * WF);
        for (int s = 0; s < NS; ++s) {
            int4   o = s_off[s];
            float4 w = s_wt[s];
            float v = src[o.x + cterm] * w.x + src[o.y + cterm] * w.y +
                      src[o.z + cterm] * w.z + src[o.w + cterm] * w.w;
            tile[s * 257 + tid] = v;
        }
        __syncthreads();
        const size_t ob = outbase + (size_t)c0 * NS;
        for (int k = tid; k < 256 * NS; k += 256) {
            int cl = k / NS;
            int s  = k - cl * NS;
            out[ob + k] = tile[s * 257 + cl];
        }
        __syncthreads();
    }
}

extern "C" void kernel_launch(void* const* d_in, const int* in_sizes, int n_in,
                              void* d_out, int out_size, void* d_ws, size_t ws_size,
                              hipStream_t stream) {
    const float* feats = (const float*)d_in[0];
    const float* boxes = (const float*)d_in[1];
    const int*   ih    = (const int*)d_in[2];
    const int*   iw    = (const int*)d_in[3];
    float*       out   = (float*)d_out;
    const int B = in_sizes[1] / 4;

    const size_t tf_bytes = (size_t)CC * HF * WF * sizeof(float);  // 32 MiB
    const size_t need = tf_bytes + (size_t)B * sizeof(int) + (size_t)NBINS * sizeof(int);
    if (ws_size >= need) {
        float* tf   = (float*)d_ws;
        int*   perm = (int*)((char*)d_ws + tf_bytes);
        int*   hist = (int*)((char*)d_ws + tf_bytes + (size_t)B * sizeof(int));
        dim3 tb(32, 8);
        dim3 tg((HF * WF) / 32, CC / 32);
        transpose_feats<<<tg, tb, 0, stream>>>(feats, tf);
        hist_zero<<<NBINS / 256, 256, 0, stream>>>(hist);
        hist_count<<<(B + 255) / 256, 256, 0, stream>>>(boxes, ih, iw, B, hist);
        hist_scan<<<1, 256, 0, stream>>>(hist);
        scatter_perm<<<(B + 255) / 256, 256, 0, stream>>>(boxes, ih, iw, B, hist, perm);
        roi_pool_v7<<<B, 256, 0, stream>>>(tf, boxes, ih, iw, perm, out);
    } else {
        roi_pool_fb<<<B, 256, 0, stream>>>(feats, boxes, ih, iw, out);
    }
}